// Round 7
// baseline (336.803 us; speedup 1.0000x reference)
//
#include <hip/hip_runtime.h>
#include <stdint.h>

typedef __bf16 bf16;
typedef __bf16 bf16x8 __attribute__((ext_vector_type(8)));
typedef __bf16 bf16x4 __attribute__((ext_vector_type(4)));
typedef float  f32x2  __attribute__((ext_vector_type(2)));
typedef float  f32x4  __attribute__((ext_vector_type(4)));
typedef float  f32x16 __attribute__((ext_vector_type(16)));
typedef float  float4v __attribute__((ext_vector_type(4)));
typedef int    int4v   __attribute__((ext_vector_type(4)));
typedef unsigned int uint;
typedef unsigned long long ull;

// log2(e)/sqrt(32): folds softmax 1/sqrt(Dh) and e^x -> 2^x into Q scaling
#define QSCALE 0.25505003984214403f

// Fragment-native layout: [bh][blk(128)][sub(4)][lane(32)][8]
// Mask M2: dword [(b*128+kdw)*4096 + q]; PERMUTED bit order within dword:
//   bit b <-> key k5 (=key%32) with b = 8*(k5&3) + (k5>>2)
// (cheap ballot byte-assembly on pack side; attn uses off = 8r+2g, shift by half)

// ---------------- K0: transpose weights -> bf16 WT[w][n][k] ----------------
__global__ __launch_bounds__(256) void transpose_w(
    const float* __restrict__ w0, const float* __restrict__ w1,
    const float* __restrict__ w2, const float* __restrict__ w3,
    bf16* __restrict__ WT) {
  const int wsel = blockIdx.z;
  const float* W = wsel == 0 ? w0 : wsel == 1 ? w1 : wsel == 2 ? w2 : w3;
  const int k0 = blockIdx.x * 64, n0 = blockIdx.y * 64;
  __shared__ __align__(16) bf16 t[64][72];
  const int tid = threadIdx.x;
  {
    const int kk = (tid >> 4) << 2;
    const int nn = (tid & 15) << 2;
#pragma unroll
    for (int r = 0; r < 4; ++r) {
      float4v a = *(const float4v*)(W + (size_t)(k0 + kk + r) * 256 + n0 + nn);
#pragma unroll
      for (int j = 0; j < 4; ++j) t[nn + j][kk + r] = (bf16)a[j];
    }
  }
  __syncthreads();
  {
    const int ni = tid >> 2;
    const int c  = (tid & 3) * 16;
    bf16x8 o0 = *(const bf16x8*)(&t[ni][c]);
    bf16x8 o1 = *(const bf16x8*)(&t[ni][c + 8]);
    bf16* dst = WT + (size_t)wsel * 65536 + (size_t)(n0 + ni) * 256 + k0 + c;
    *(bf16x8*)dst = o0;
    *(bf16x8*)(dst + 8) = o1;
  }
}

// ---------------- K1: fused pack_mask (blocks 0..1023) + proj (1024..1791) ----
__global__ __launch_bounds__(256) void proj_pack(
    const float* __restrict__ xq, const float* __restrict__ xk, const float* __restrict__ xv,
    const bf16* __restrict__ WT,
    bf16* __restrict__ Qp, bf16* __restrict__ Kp, bf16* __restrict__ Vp,
    const int* __restrict__ mask, uint* __restrict__ M2) {
  __shared__ __align__(16) unsigned char smem[18432];
  const int tid = threadIdx.x;

  if (blockIdx.x < 1024) {
    // ---- pack_mask: tile 32 q x 1024 k; m13-pattern contiguous 16B/lane loads ----
    // Each wave packs 8 q rows x 4 k-chunks (32 iters), covering all 32 q rows.
    uint* trans = (uint*)smem;                    // [32 kdw][36 pitch] dwords
    const int pid = blockIdx.x;
    const int bb = pid >> 9;
    const int qt = (pid >> 2) & 127;
    const int kc = pid & 3;
    const int q0 = qt * 32;
    const int w = tid >> 6, l = tid & 63;
    const int d2 = l & 7;
    const int sh = 8 * d2;
#pragma unroll 4
    for (int t = 0; t < 32; ++t) {
      const int q_l = w * 8 + (t >> 2), c = t & 3;
      const int4v m = *(const int4v*)(mask + ((size_t)(bb * 4096 + q0 + q_l)) * 4096 +
                                      kc * 1024 + c * 256 + 4 * l);
      uint out = 0;
#pragma unroll
      for (int i = 0; i < 4; ++i) {
        ull b = __ballot(m[i] != 0);
        out |= ((uint)(b >> sh) & 0xFFu) << (8 * i);
      }
      if (l < 8) trans[(c * 8 + d2) * 36 + q_l] = out;
    }
    __syncthreads();
    {
      const int r = tid >> 3, c4 = (tid & 7) * 4;
      int4v a = *(const int4v*)(trans + r * 36 + c4);
      *(int4v*)(M2 + ((size_t)(bb * 128 + kc * 32 + r)) * 4096 + q0 + c4) = a;
    }
    return;
  }

  // ---- proj: 64 pos x 128 cols tile, epilogue through LDS for coalesced stores ----
  const int pb = blockIdx.x - 1024;
  const int z = pb >> 8;
  const int r8 = pb & 255;
  const int m0 = (r8 >> 1) * 64, n0 = (r8 & 1) * 128;
  const float* X = z == 0 ? xq : (z == 1 ? xk : xv);
  const bf16* wt = WT + (size_t)z * 65536;
  const int wave = tid >> 6, lane = tid & 63;
  const int nl = lane & 15, quad = lane >> 4;
  const int arow = m0 + wave * 16 + nl;
  const float* xrow = X + (size_t)arow * 256;

  f32x4 zero4 = {0.f, 0.f, 0.f, 0.f};
  f32x4 acc[8];
#pragma unroll
  for (int i = 0; i < 8; ++i) acc[i] = zero4;

  for (int ks = 0; ks < 8; ++ks) {
    float4v a0 = *(const float4v*)(xrow + ks * 32 + quad * 8);
    float4v a1 = *(const float4v*)(xrow + ks * 32 + quad * 8 + 4);
    bf16x8 af;
#pragma unroll
    for (int i = 0; i < 4; ++i) { af[i] = (bf16)a0[i]; af[4 + i] = (bf16)a1[i]; }
#pragma unroll
    for (int nf = 0; nf < 8; ++nf) {
      bf16x8 bfr = *(const bf16x8*)(wt + (size_t)(n0 + nf * 16 + nl) * 256 + ks * 32 + quad * 8);
      acc[nf] = __builtin_amdgcn_mfma_f32_16x16x32_bf16(af, bfr, acc[nf], 0, 0, 0);
    }
  }

  const int bq = m0 >> 12;
  const int s0 = m0 & 4095;
  const int posl = wave * 16 + quad * 4;

  if (z == 2) {
    bf16* tv = (bf16*)smem;                       // [col(128)][key(64)+8] pitch 72
#pragma unroll
    for (int nf = 0; nf < 8; ++nf) {
      const int col = nf * 16 + nl;
      bf16x4 o;
#pragma unroll
      for (int rr = 0; rr < 4; ++rr) o[rr] = (bf16)acc[nf][rr];
      *(bf16x4*)(tv + (size_t)col * 72 + posl) = o;
    }
    __syncthreads();
    const int h2 = tid >> 6, ln = tid & 63;
    const int d = ln & 31, shalf = ln >> 5;
    const int h = (n0 >> 5) + h2;
    bf16* vb = Vp + (size_t)(bq * 8 + h) * 131072 + (size_t)(s0 >> 5) * 1024 + d * 8;
#pragma unroll
    for (int it = 0; it < 4; ++it) {
      const int blk = it >> 1, sub = (it & 1) * 2 + shalf;
      const int K0 = (sub >> 1) * 16 + (sub & 1) * 4;
      const bf16* src = tv + (size_t)(h2 * 32 + d) * 72 + blk * 32 + K0;
      bf16x4 g0 = *(const bf16x4*)(src);
      bf16x4 g1 = *(const bf16x4*)(src + 8);
      bf16x8 o;
#pragma unroll
      for (int j = 0; j < 4; ++j) { o[j] = g0[j]; o[4 + j] = g1[j]; }
      *(bf16x8*)(vb + (size_t)blk * 1024 + sub * 256) = o;
    }
  } else {
    bf16* tq = (bf16*)smem;                       // [pos(64)][col(128)+8] pitch 136
    const float scale = (z == 0) ? QSCALE : 1.0f;
#pragma unroll
    for (int nf = 0; nf < 8; ++nf) {
      const int col = nf * 16 + nl;
#pragma unroll
      for (int rr = 0; rr < 4; ++rr)
        tq[(size_t)(posl + rr) * 136 + col] = (bf16)(acc[nf][rr] * scale);
    }
    __syncthreads();
    bf16* Out = z == 0 ? Qp : Kp;
    const int h2 = tid >> 6, ln = tid & 63;
    const int h = (n0 >> 5) + h2;
    const int s = s0 + ln;
    bf16* ob = Out + (size_t)(bq * 8 + h) * 131072 + (size_t)(s >> 5) * 1024 + (s & 31) * 8;
#pragma unroll
    for (int sub = 0; sub < 4; ++sub) {
      bf16x8 o = *(const bf16x8*)(tq + (size_t)ln * 136 + h2 * 32 + sub * 8);
      *(bf16x8*)(ob + sub * 256) = o;
    }
  }
}

// ---------------- K3: attention — 32x32x16, zero LDS in K-loop ----------------
__global__ __launch_bounds__(256) void attn_kernel(
    const bf16* __restrict__ Qp, const bf16* __restrict__ Kp,
    const bf16* __restrict__ Vp, const uint* __restrict__ M2,
    bf16* __restrict__ Og) {
  const int id = blockIdx.x;
  const int xcd = id & 7, slot = id >> 3;
  const int bh = xcd * 2 + (slot >> 6);      // 2 bh per XCD -> L2-resident K/V/mask
  const int q0 = (slot & 63) * 64;
  const int b = bh >> 3, h = bh & 7;
  const int tid = threadIdx.x, w = tid >> 6, lane = tid & 63;
  const int nl = lane & 31, half = lane >> 5;

  __shared__ float Ored[4][32][66];
  __shared__ float Lsum[64][8];

  const size_t bhbase = (size_t)bh * 131072;
  const int so0 = half * 256 + nl * 8;
  const int so1 = 512 + half * 256 + nl * 8;

  bf16x8 qf[2][2];
#pragma unroll
  for (int qt = 0; qt < 2; ++qt) {
    const bf16* qb = Qp + bhbase + (size_t)((q0 >> 5) + qt) * 1024;
    qf[qt][0] = *(const bf16x8*)(qb + so0);
    qf[qt][1] = *(const bf16x8*)(qb + so1);
  }

  const bf16* Kw = Kp + bhbase + (size_t)w * 1024;
  const bf16* Vw = Vp + bhbase + (size_t)w * 1024;
  const uint* Mw = M2 + (size_t)b * 524288 + (size_t)w * 4096 + q0 + nl;

  f32x16 z16;
#pragma unroll
  for (int i = 0; i < 16; ++i) z16[i] = 0.f;
  f32x16 acc0 = z16, acc1 = z16;
  f32x2 ls0 = {0.f, 0.f}, ls1 = {0.f, 0.f};

  struct Frag { bf16x8 ka0, ka1, va0, va1; uint m0, m1; };
  auto LOADF = [&](int kt) -> Frag {
    Frag f;
    const bf16* kc = Kw + (size_t)kt * 4096;
    const bf16* vc = Vw + (size_t)kt * 4096;
    f.ka0 = *(const bf16x8*)(kc + so0);
    f.ka1 = *(const bf16x8*)(kc + so1);
    f.va0 = *(const bf16x8*)(vc + so0);
    f.va1 = *(const bf16x8*)(vc + so1);
    const uint* mp = Mw + (size_t)kt * 16384;
    f.m0 = mp[0];
    f.m1 = mp[32];
    return f;
  };

  auto STEP = [&](const Frag& f) {
    // permuted bit order: key k5 = r+8g+4half -> bit 8r+2g+half
    const int minv0 = (int)((~f.m0) >> half);
    const int minv1 = (int)((~f.m1) >> half);
    f32x16 st0 = __builtin_amdgcn_mfma_f32_32x32x16_bf16(f.ka0, qf[0][0], z16, 0, 0, 0);
    st0 = __builtin_amdgcn_mfma_f32_32x32x16_bf16(f.ka1, qf[0][1], st0, 0, 0, 0);
    f32x16 st1 = __builtin_amdgcn_mfma_f32_32x32x16_bf16(f.ka0, qf[1][0], z16, 0, 0, 0);
    st1 = __builtin_amdgcn_mfma_f32_32x32x16_bf16(f.ka1, qf[1][1], st1, 0, 0, 0);

    f32x16 pf0, pf1;
#pragma unroll
    for (int g = 0; g < 4; ++g)
#pragma unroll
      for (int r = 0; r < 4; ++r) {
        const int i = g * 4 + r, off = 8 * r + 2 * g;
        float e0 = __builtin_amdgcn_exp2f(st0[i]);
        float e1 = __builtin_amdgcn_exp2f(st1[i]);
        const uint k0m = (uint)__builtin_amdgcn_sbfe(minv0, off, 1);
        const uint k1m = (uint)__builtin_amdgcn_sbfe(minv1, off, 1);
        e0 = __uint_as_float(__float_as_uint(e0) & k0m);
        e1 = __uint_as_float(__float_as_uint(e1) & k1m);
        pf0[i] = e0; pf1[i] = e1;
      }
#pragma unroll
    for (int i = 0; i < 16; i += 2) {
      f32x2 a0 = {pf0[i], pf0[i + 1]};
      f32x2 a1 = {pf1[i], pf1[i + 1]};
      ls0 += a0; ls1 += a1;
    }
    const bf16x8 pb00 = __builtin_convertvector(
        __builtin_shufflevector(pf0, pf0, 0, 1, 2, 3, 4, 5, 6, 7), bf16x8);
    const bf16x8 pb01 = __builtin_convertvector(
        __builtin_shufflevector(pf0, pf0, 8, 9, 10, 11, 12, 13, 14, 15), bf16x8);
    const bf16x8 pb10 = __builtin_convertvector(
        __builtin_shufflevector(pf1, pf1, 0, 1, 2, 3, 4, 5, 6, 7), bf16x8);
    const bf16x8 pb11 = __builtin_convertvector(
        __builtin_shufflevector(pf1, pf1, 8, 9, 10, 11, 12, 13, 14, 15), bf16x8);

    acc0 = __builtin_amdgcn_mfma_f32_32x32x16_bf16(f.va0, pb00, acc0, 0, 0, 0);
    acc0 = __builtin_amdgcn_mfma_f32_32x32x16_bf16(f.va1, pb01, acc0, 0, 0, 0);
    acc1 = __builtin_amdgcn_mfma_f32_32x32x16_bf16(f.va0, pb10, acc1, 0, 0, 0);
    acc1 = __builtin_amdgcn_mfma_f32_32x32x16_bf16(f.va1, pb11, acc1, 0, 0, 0);
  };

  Frag fa = LOADF(0), fb;
  for (int kt = 0; kt < 32; kt += 2) {
    fb = LOADF(kt + 1);
    STEP(fa);
    if (kt + 2 < 32) fa = LOADF(kt + 2);
    STEP(fb);
  }

  // ---- epilogue: cross-wave reduce ----
#pragma unroll
  for (int g = 0; g < 4; ++g)
#pragma unroll
    for (int r = 0; r < 4; ++r) {
      const int d = r + 8 * g + 4 * half, i = g * 4 + r;
      Ored[w][d][nl] = acc0[i];
      Ored[w][d][32 + nl] = acc1[i];
    }
  Lsum[nl][w * 2 + half] = ls0.x + ls0.y;
  Lsum[32 + nl][w * 2 + half] = ls1.x + ls1.y;
  __syncthreads();
  if (tid < 64) {
    float s = 0.f;
#pragma unroll
    for (int j = 0; j < 8; ++j) s += Lsum[tid][j];
    Lsum[tid][0] = 1.0f / s;
  }
  __syncthreads();
  {
    const int q = tid >> 2, db = (tid & 3) * 8;
    const float rl = Lsum[q][0];
    bf16x8 o;
#pragma unroll
    for (int dj = 0; dj < 8; ++dj) {
      const float s = Ored[0][db + dj][q] + Ored[1][db + dj][q] +
                      Ored[2][db + dj][q] + Ored[3][db + dj][q];
      o[dj] = (bf16)(s * rl);
    }
    *(bf16x8*)(Og + ((size_t)(b * 4096 + q0 + q)) * 256 + h * 32 + db) = o;
  }
}

// ---------------- K4: out = attn(bf16) @ w_out -> fp32, 64x64 tiles ----------------
__global__ __launch_bounds__(256) void gemm_out(
    const bf16* __restrict__ A, const bf16* __restrict__ WTo, float* __restrict__ C) {
  const int m0 = blockIdx.x * 64, n0 = blockIdx.y * 64;
  const int tid = threadIdx.x, wave = tid >> 6, lane = tid & 63;
  const int nl = lane & 15, quad = lane >> 4;
  const int arow = m0 + wave * 16 + nl;

  f32x4 zero4 = {0.f, 0.f, 0.f, 0.f};
  f32x4 acc[4];
#pragma unroll
  for (int i = 0; i < 4; ++i) acc[i] = zero4;

  for (int ks = 0; ks < 8; ++ks) {
    bf16x8 af = *(const bf16x8*)(A + (size_t)arow * 256 + ks * 32 + quad * 8);
#pragma unroll
    for (int nf = 0; nf < 4; ++nf) {
      bf16x8 bfr = *(const bf16x8*)(WTo + (size_t)(n0 + nf * 16 + nl) * 256 + ks * 32 + quad * 8);
      acc[nf] = __builtin_amdgcn_mfma_f32_16x16x32_bf16(af, bfr, acc[nf], 0, 0, 0);
    }
  }
  const int Rbase = m0 + wave * 16 + quad * 4;
#pragma unroll
  for (int nf = 0; nf < 4; ++nf)
#pragma unroll
    for (int r = 0; r < 4; ++r)
      C[(size_t)(Rbase + r) * 256 + n0 + nf * 16 + nl] = acc[nf][r];
}

extern "C" void kernel_launch(void* const* d_in, const int* in_sizes, int n_in,
                              void* d_out, int out_size, void* d_ws, size_t ws_size,
                              hipStream_t stream) {
  const float* q  = (const float*)d_in[0];
  const float* k  = (const float*)d_in[1];
  const float* v  = (const float*)d_in[2];
  const int*  mask = (const int*)d_in[3];
  const float* wq = (const float*)d_in[4];
  const float* wk = (const float*)d_in[5];
  const float* wv = (const float*)d_in[6];
  const float* wo = (const float*)d_in[7];
  float* out = (float*)d_out;

  uint8_t* ws = (uint8_t*)d_ws;
  bf16* WT = (bf16*)ws;                               // 512 KB
  bf16* Qp = (bf16*)(ws + (512u << 10));              // frag-native 4 MB
  bf16* Kp = Qp + 2097152;                            // 4 MB
  bf16* Vp = Kp + 2097152;                            // 4 MB
  uint* Mb = (uint*)((uint8_t*)(Vp + 2097152));       // packed mask (permuted bits) 4 MB
  bf16* Ao = (bf16*)((uint8_t*)Mb + (4u << 20));      // attn bf16 [B,S,256] 4 MB

  transpose_w<<<dim3(4, 4, 4), 256, 0, stream>>>(wq, wk, wv, wo, WT);
  proj_pack<<<dim3(1024 + 768), 256, 0, stream>>>(q, k, v, WT, Qp, Kp, Vp, mask, Mb);
  attn_kernel<<<dim3(1024), 256, 0, stream>>>(Qp, Kp, Vp, Mb, Ao);
  gemm_out<<<dim3(128, 4), 256, 0, stream>>>(Ao, WT + 3 * 65536, out);
}

// Round 8
// 333.924 us; speedup vs baseline: 1.0086x; 1.0086x over previous
//
#include <hip/hip_runtime.h>
#include <stdint.h>

typedef __bf16 bf16;
typedef __bf16 bf16x2 __attribute__((ext_vector_type(2)));
typedef __bf16 bf16x4 __attribute__((ext_vector_type(4)));
typedef __bf16 bf16x8 __attribute__((ext_vector_type(8)));
typedef float  f32x4  __attribute__((ext_vector_type(4)));
typedef float  f32x16 __attribute__((ext_vector_type(16)));
typedef float  float4v __attribute__((ext_vector_type(4)));
typedef int    int4v   __attribute__((ext_vector_type(4)));
typedef unsigned int uint;
typedef uint   uint4v  __attribute__((ext_vector_type(4)));
typedef unsigned long long ull;

// log2(e)/sqrt(32): folds softmax 1/sqrt(Dh) and e^x -> 2^x into Q scaling
#define QSCALE 0.25505003984214403f

// Fragment-native layout: [bh][blk(128)][sub(4)][lane(32)][8]
// Mask M2: dword [(b*128+kdw)*4096 + q]; permuted bit order (R7-verified):
//   key k5 = r+8g+4*half  <->  bit 8r+2g+half

// ---------------- K0: transpose weights -> bf16 WT[w][n][k] ----------------
__global__ __launch_bounds__(256) void transpose_w(
    const float* __restrict__ w0, const float* __restrict__ w1,
    const float* __restrict__ w2, const float* __restrict__ w3,
    bf16* __restrict__ WT) {
  const int wsel = blockIdx.z;
  const float* W = wsel == 0 ? w0 : wsel == 1 ? w1 : wsel == 2 ? w2 : w3;
  const int k0 = blockIdx.x * 64, n0 = blockIdx.y * 64;
  __shared__ __align__(16) bf16 t[64][72];
  const int tid = threadIdx.x;
  {
    const int kk = (tid >> 4) << 2;
    const int nn = (tid & 15) << 2;
#pragma unroll
    for (int r = 0; r < 4; ++r) {
      float4v a = *(const float4v*)(W + (size_t)(k0 + kk + r) * 256 + n0 + nn);
#pragma unroll
      for (int j = 0; j < 4; ++j) t[nn + j][kk + r] = (bf16)a[j];
    }
  }
  __syncthreads();
  {
    const int ni = tid >> 2;
    const int c  = (tid & 3) * 16;
    bf16x8 o0 = *(const bf16x8*)(&t[ni][c]);
    bf16x8 o1 = *(const bf16x8*)(&t[ni][c + 8]);
    bf16* dst = WT + (size_t)wsel * 65536 + (size_t)(n0 + ni) * 256 + k0 + c;
    *(bf16x8*)dst = o0;
    *(bf16x8*)(dst + 8) = o1;
  }
}

// ---------------- K1: fused pack_mask (blocks 0..1023) + proj (1024..1791) ----
__global__ __launch_bounds__(256) void proj_pack(
    const float* __restrict__ xq, const float* __restrict__ xk, const float* __restrict__ xv,
    const bf16* __restrict__ WT,
    bf16* __restrict__ Qp, bf16* __restrict__ Kp, bf16* __restrict__ Vp,
    const int* __restrict__ mask, uint* __restrict__ M2) {
  __shared__ __align__(16) unsigned char smem[18432];
  const int tid = threadIdx.x;

  if (blockIdx.x < 1024) {
    // ---- pack_mask: 32 q x 1024 k tile; 8 int4 loads in flight per batch ----
    uint* trans = (uint*)smem;                    // [32 kdw][36 pitch] dwords
    const int pid = blockIdx.x;
    const int bb = pid >> 9;
    const int qt = (pid >> 2) & 127;
    const int kc = pid & 3;
    const int q0 = qt * 32;
    const int w = tid >> 6, l = tid & 63;
    const int d2 = l & 7;
    const int sh = 8 * d2;
    for (int batch = 0; batch < 4; ++batch) {
      int4v m[8];
#pragma unroll
      for (int u = 0; u < 8; ++u) {
        const int q_l = w * 8 + batch * 2 + (u >> 2);
        const int c = u & 3;
        m[u] = *(const int4v*)(mask + ((size_t)(bb * 4096 + q0 + q_l)) * 4096 +
                               kc * 1024 + c * 256 + 4 * l);
      }
#pragma unroll
      for (int u = 0; u < 8; ++u) {
        const int q_l = w * 8 + batch * 2 + (u >> 2);
        const int c = u & 3;
        uint out = 0;
#pragma unroll
        for (int i = 0; i < 4; ++i) {
          ull b = __ballot(m[u][i] != 0);
          out |= ((uint)(b >> sh) & 0xFFu) << (8 * i);
        }
        if (l < 8) trans[(c * 8 + d2) * 36 + q_l] = out;
      }
    }
    __syncthreads();
    {
      const int r = tid >> 3, c4 = (tid & 7) * 4;
      int4v a = *(const int4v*)(trans + r * 36 + c4);
      *(int4v*)(M2 + ((size_t)(bb * 128 + kc * 32 + r)) * 4096 + q0 + c4) = a;
    }
    return;
  }

  // ---- proj: 64 pos x 128 cols tile, epilogue through LDS for coalesced stores ----
  const int pb = blockIdx.x - 1024;
  const int z = pb >> 8;
  const int r8 = pb & 255;
  const int m0 = (r8 >> 1) * 64, n0 = (r8 & 1) * 128;
  const float* X = z == 0 ? xq : (z == 1 ? xk : xv);
  const bf16* wt = WT + (size_t)z * 65536;
  const int wave = tid >> 6, lane = tid & 63;
  const int nl = lane & 15, quad = lane >> 4;
  const int arow = m0 + wave * 16 + nl;
  const float* xrow = X + (size_t)arow * 256;

  f32x4 zero4 = {0.f, 0.f, 0.f, 0.f};
  f32x4 acc[8];
#pragma unroll
  for (int i = 0; i < 8; ++i) acc[i] = zero4;

  for (int ks = 0; ks < 8; ++ks) {
    float4v a0 = *(const float4v*)(xrow + ks * 32 + quad * 8);
    float4v a1 = *(const float4v*)(xrow + ks * 32 + quad * 8 + 4);
    bf16x8 af;
#pragma unroll
    for (int i = 0; i < 4; ++i) { af[i] = (bf16)a0[i]; af[4 + i] = (bf16)a1[i]; }
#pragma unroll
    for (int nf = 0; nf < 8; ++nf) {
      bf16x8 bfr = *(const bf16x8*)(wt + (size_t)(n0 + nf * 16 + nl) * 256 + ks * 32 + quad * 8);
      acc[nf] = __builtin_amdgcn_mfma_f32_16x16x32_bf16(af, bfr, acc[nf], 0, 0, 0);
    }
  }

  const int bq = m0 >> 12;
  const int s0 = m0 & 4095;
  const int posl = wave * 16 + quad * 4;

  if (z == 2) {
    bf16* tv = (bf16*)smem;                       // [col(128)][key(64)+8] pitch 72
#pragma unroll
    for (int nf = 0; nf < 8; ++nf) {
      const int col = nf * 16 + nl;
      bf16x4 o;
#pragma unroll
      for (int rr = 0; rr < 4; ++rr) o[rr] = (bf16)acc[nf][rr];
      *(bf16x4*)(tv + (size_t)col * 72 + posl) = o;
    }
    __syncthreads();
    const int h2 = tid >> 6, ln = tid & 63;
    const int d = ln & 31, shalf = ln >> 5;
    const int h = (n0 >> 5) + h2;
    bf16* vb = Vp + (size_t)(bq * 8 + h) * 131072 + (size_t)(s0 >> 5) * 1024 + d * 8;
#pragma unroll
    for (int it = 0; it < 4; ++it) {
      const int blk = it >> 1, sub = (it & 1) * 2 + shalf;
      const int K0 = (sub >> 1) * 16 + (sub & 1) * 4;
      const bf16* src = tv + (size_t)(h2 * 32 + d) * 72 + blk * 32 + K0;
      bf16x4 g0 = *(const bf16x4*)(src);
      bf16x4 g1 = *(const bf16x4*)(src + 8);
      bf16x8 o;
#pragma unroll
      for (int j = 0; j < 4; ++j) { o[j] = g0[j]; o[4 + j] = g1[j]; }
      *(bf16x8*)(vb + (size_t)blk * 1024 + sub * 256) = o;
    }
  } else {
    bf16* tq = (bf16*)smem;                       // [pos(64)][col(128)+8] pitch 136
    const float scale = (z == 0) ? QSCALE : 1.0f;
#pragma unroll
    for (int nf = 0; nf < 8; ++nf) {
      const int col = nf * 16 + nl;
#pragma unroll
      for (int rr = 0; rr < 4; ++rr)
        tq[(size_t)(posl + rr) * 136 + col] = (bf16)(acc[nf][rr] * scale);
    }
    __syncthreads();
    bf16* Out = z == 0 ? Qp : Kp;
    const int h2 = tid >> 6, ln = tid & 63;
    const int h = (n0 >> 5) + h2;
    const int s = s0 + ln;
    bf16* ob = Out + (size_t)(bq * 8 + h) * 131072 + (size_t)(s >> 5) * 1024 + (s & 31) * 8;
#pragma unroll
    for (int sub = 0; sub < 4; ++sub) {
      bf16x8 o = *(const bf16x8*)(tq + (size_t)ln * 136 + h2 * 32 + sub * 8);
      *(bf16x8*)(ob + sub * 256) = o;
    }
  }
}

// ---------------- K3: attention — wave owns 32 q x ALL keys; no cross-wave
// reduction; lsum via ones-A MFMA; bf16 pack via v_perm (truncation — bias
// cancels in O = sum(pV)/sum(p)). 2-wave blocks, tiny LDS.
__global__ __launch_bounds__(128, 3) void attn_kernel(
    const bf16* __restrict__ Qp, const bf16* __restrict__ Kp,
    const bf16* __restrict__ Vp, const uint* __restrict__ M2,
    bf16* __restrict__ Og) {
  const int id = blockIdx.x;
  const int xcd = id & 7, slot = id >> 3;
  const int bh = xcd * 2 + (slot >> 6);      // 2 bh per XCD -> L2-resident K/V/mask
  const int qt = slot & 63;                  // 64-q tile per block
  const int b = bh >> 3, h = bh & 7;
  const int tid = threadIdx.x, w = tid >> 6, lane = tid & 63;
  const int nl = lane & 31, half = lane >> 5;

  __shared__ __align__(16) bf16 T[64][40];   // 5 KB epilogue staging

  const size_t bhbase = (size_t)bh * 131072;
  const int so0 = half * 256 + nl * 8;
  const int so1 = 512 + half * 256 + nl * 8;
  const int qg = qt * 64 + w * 32;           // wave's global q base

  const bf16* qb = Qp + bhbase + (size_t)(qg >> 5) * 1024;
  const bf16x8 qf0 = *(const bf16x8*)(qb + so0);
  const bf16x8 qf1 = *(const bf16x8*)(qb + so1);

  const bf16* Kb = Kp + bhbase;
  const bf16* Vb = Vp + bhbase;
  const uint* Mb = M2 + (size_t)b * 524288 + qg + nl;

  f32x16 z16;
#pragma unroll
  for (int i = 0; i < 16; ++i) z16[i] = 0.f;
  f32x16 acc = z16, lacc = z16;
  bf16x8 ones;
#pragma unroll
  for (int i = 0; i < 8; ++i) ones[i] = (bf16)1.0f;

  struct Frag { bf16x8 ka0, ka1, va0, va1; uint m; };
  auto LOADF = [&](int kdw) -> Frag {
    Frag f;
    const bf16* kc = Kb + (size_t)kdw * 1024;
    const bf16* vc = Vb + (size_t)kdw * 1024;
    f.ka0 = *(const bf16x8*)(kc + so0);
    f.ka1 = *(const bf16x8*)(kc + so1);
    f.va0 = *(const bf16x8*)(vc + so0);
    f.va1 = *(const bf16x8*)(vc + so1);
    f.m = Mb[(size_t)kdw * 4096];
    return f;
  };

  auto STEP = [&](const Frag& f) {
    const int minv = (int)((~f.m) >> half);
    f32x16 st = __builtin_amdgcn_mfma_f32_32x32x16_bf16(f.ka0, qf0, z16, 0, 0, 0);
    st = __builtin_amdgcn_mfma_f32_32x32x16_bf16(f.ka1, qf1, st, 0, 0, 0);

    uint pk[8];
#pragma unroll
    for (int g = 0; g < 4; ++g)
#pragma unroll
      for (int rp = 0; rp < 2; ++rp) {
        const int i = g * 4 + rp * 2;
        float e0 = __builtin_amdgcn_exp2f(st[i]);
        float e1 = __builtin_amdgcn_exp2f(st[i + 1]);
        const uint k0m = (uint)__builtin_amdgcn_sbfe(minv, 8 * (2 * rp) + 2 * g, 1);
        const uint k1m = (uint)__builtin_amdgcn_sbfe(minv, 8 * (2 * rp + 1) + 2 * g, 1);
        const uint u0 = __float_as_uint(e0) & k0m;
        const uint u1 = __float_as_uint(e1) & k1m;
        pk[g * 2 + rp] = __builtin_amdgcn_perm(u1, u0, 0x07060302u);  // {hi16(u1),hi16(u0)}
      }
    uint4v a0 = {pk[0], pk[1], pk[2], pk[3]};
    uint4v a1 = {pk[4], pk[5], pk[6], pk[7]};
    const bf16x8 pb0 = __builtin_bit_cast(bf16x8, a0);
    const bf16x8 pb1 = __builtin_bit_cast(bf16x8, a1);

    acc  = __builtin_amdgcn_mfma_f32_32x32x16_bf16(f.va0, pb0, acc, 0, 0, 0);
    lacc = __builtin_amdgcn_mfma_f32_32x32x16_bf16(ones,  pb0, lacc, 0, 0, 0);
    acc  = __builtin_amdgcn_mfma_f32_32x32x16_bf16(f.va1, pb1, acc, 0, 0, 0);
    lacc = __builtin_amdgcn_mfma_f32_32x32x16_bf16(ones,  pb1, lacc, 0, 0, 0);
  };

  Frag fa = LOADF(0), fb;
  for (int kdw = 0; kdw < 128; kdw += 2) {
    fb = LOADF(kdw + 1);
    STEP(fa);
    if (kdw + 2 < 128) fa = LOADF(kdw + 2);
    STEP(fb);
  }

  // ---- epilogue: normalize (lacc rows all = lsum(q)), stage via LDS ----
  const float rl = 1.0f / lacc[0];
#pragma unroll
  for (int g = 0; g < 4; ++g)
#pragma unroll
    for (int rp = 0; rp < 2; ++rp) {
      const int i = g * 4 + rp * 2;
      const int d = rp * 2 + 8 * g + 4 * half;
      bf16x2 o;
      o[0] = (bf16)(acc[i] * rl);
      o[1] = (bf16)(acc[i + 1] * rl);
      *(bf16x2*)(&T[w * 32 + nl][d]) = o;
    }
  __syncthreads();
  {
    const int ql = tid & 63, rep = tid >> 6;
    bf16* obase = Og + ((size_t)(b * 4096 + qt * 64 + ql)) * 256 + h * 32;
#pragma unroll
    for (int c = 0; c < 2; ++c) {
      const int chunk = rep * 2 + c;
      bf16x8 o = *(const bf16x8*)(&T[ql][chunk * 8]);
      *(bf16x8*)(obase + chunk * 8) = o;
    }
  }
}

// ---------------- K4: out = attn(bf16) @ w_out -> fp32, 64x64 tiles ----------------
__global__ __launch_bounds__(256) void gemm_out(
    const bf16* __restrict__ A, const bf16* __restrict__ WTo, float* __restrict__ C) {
  const int m0 = blockIdx.x * 64, n0 = blockIdx.y * 64;
  const int tid = threadIdx.x, wave = tid >> 6, lane = tid & 63;
  const int nl = lane & 15, quad = lane >> 4;
  const int arow = m0 + wave * 16 + nl;

  f32x4 zero4 = {0.f, 0.f, 0.f, 0.f};
  f32x4 acc[4];
#pragma unroll
  for (int i = 0; i < 4; ++i) acc[i] = zero4;

  for (int ks = 0; ks < 8; ++ks) {
    bf16x8 af = *(const bf16x8*)(A + (size_t)arow * 256 + ks * 32 + quad * 8);
#pragma unroll
    for (int nf = 0; nf < 4; ++nf) {
      bf16x8 bfr = *(const bf16x8*)(WTo + (size_t)(n0 + nf * 16 + nl) * 256 + ks * 32 + quad * 8);
      acc[nf] = __builtin_amdgcn_mfma_f32_16x16x32_bf16(af, bfr, acc[nf], 0, 0, 0);
    }
  }
  const int Rbase = m0 + wave * 16 + quad * 4;
#pragma unroll
  for (int nf = 0; nf < 4; ++nf)
#pragma unroll
    for (int r = 0; r < 4; ++r)
      C[(size_t)(Rbase + r) * 256 + n0 + nf * 16 + nl] = acc[nf][r];
}

extern "C" void kernel_launch(void* const* d_in, const int* in_sizes, int n_in,
                              void* d_out, int out_size, void* d_ws, size_t ws_size,
                              hipStream_t stream) {
  const float* q  = (const float*)d_in[0];
  const float* k  = (const float*)d_in[1];
  const float* v  = (const float*)d_in[2];
  const int*  mask = (const int*)d_in[3];
  const float* wq = (const float*)d_in[4];
  const float* wk = (const float*)d_in[5];
  const float* wv = (const float*)d_in[6];
  const float* wo = (const float*)d_in[7];
  float* out = (float*)d_out;

  uint8_t* ws = (uint8_t*)d_ws;
  bf16* WT = (bf16*)ws;                               // 512 KB
  bf16* Qp = (bf16*)(ws + (512u << 10));              // frag-native 4 MB
  bf16* Kp = Qp + 2097152;                            // 4 MB
  bf16* Vp = Kp + 2097152;                            // 4 MB
  uint* Mb = (uint*)((uint8_t*)(Vp + 2097152));       // packed mask (permuted bits) 4 MB
  bf16* Ao = (bf16*)((uint8_t*)Mb + (4u << 20));      // attn bf16 [B,S,256] 4 MB

  transpose_w<<<dim3(4, 4, 4), 256, 0, stream>>>(wq, wk, wv, wo, WT);
  proj_pack<<<dim3(1024 + 768), 256, 0, stream>>>(q, k, v, WT, Qp, Kp, Vp, mask, Mb);
  attn_kernel<<<dim3(1024), 128, 0, stream>>>(Qp, Kp, Vp, Mb, Ao);
  gemm_out<<<dim3(128, 4), 256, 0, stream>>>(Ao, WT + 3 * 65536, out);
}

// Round 9
// 330.954 us; speedup vs baseline: 1.0177x; 1.0090x over previous
//
#include <hip/hip_runtime.h>
#include <stdint.h>

typedef __bf16 bf16;
typedef __bf16 bf16x2 __attribute__((ext_vector_type(2)));
typedef __bf16 bf16x4 __attribute__((ext_vector_type(4)));
typedef __bf16 bf16x8 __attribute__((ext_vector_type(8)));
typedef float  f32x4  __attribute__((ext_vector_type(4)));
typedef float  f32x16 __attribute__((ext_vector_type(16)));
typedef float  float4v __attribute__((ext_vector_type(4)));
typedef int    int4v   __attribute__((ext_vector_type(4)));
typedef unsigned int uint;
typedef uint   uint4v  __attribute__((ext_vector_type(4)));
typedef unsigned long long ull;

// log2(e)/sqrt(32): folds softmax 1/sqrt(Dh) and e^x -> 2^x into Q scaling
#define QSCALE 0.25505003984214403f

// Fragment-native layout: [bh][blk(128)][sub(4)][lane(32)][8]
// Mask M2: dword [(b*128+kdw)*4096 + q]; permuted bit order (R7/R8-verified):
//   key k5 = r+8g+4*half  <->  bit 8r+2g+half

// ---------------- K0: transpose weights -> bf16 WT[w][n][k] ----------------
__global__ __launch_bounds__(256) void transpose_w(
    const float* __restrict__ w0, const float* __restrict__ w1,
    const float* __restrict__ w2, const float* __restrict__ w3,
    bf16* __restrict__ WT) {
  const int wsel = blockIdx.z;
  const float* W = wsel == 0 ? w0 : wsel == 1 ? w1 : wsel == 2 ? w2 : w3;
  const int k0 = blockIdx.x * 64, n0 = blockIdx.y * 64;
  __shared__ __align__(16) bf16 t[64][72];
  const int tid = threadIdx.x;
  {
    const int kk = (tid >> 4) << 2;
    const int nn = (tid & 15) << 2;
#pragma unroll
    for (int r = 0; r < 4; ++r) {
      float4v a = *(const float4v*)(W + (size_t)(k0 + kk + r) * 256 + n0 + nn);
#pragma unroll
      for (int j = 0; j < 4; ++j) t[nn + j][kk + r] = (bf16)a[j];
    }
  }
  __syncthreads();
  {
    const int ni = tid >> 2;
    const int c  = (tid & 3) * 16;
    bf16x8 o0 = *(const bf16x8*)(&t[ni][c]);
    bf16x8 o1 = *(const bf16x8*)(&t[ni][c + 8]);
    bf16* dst = WT + (size_t)wsel * 65536 + (size_t)(n0 + ni) * 256 + k0 + c;
    *(bf16x8*)dst = o0;
    *(bf16x8*)(dst + 8) = o1;
  }
}

// ---------------- K1: fused pack_mask (blocks 0..1023) + proj (1024..1791) ----
__global__ __launch_bounds__(256) void proj_pack(
    const float* __restrict__ xq, const float* __restrict__ xk, const float* __restrict__ xv,
    const bf16* __restrict__ WT,
    bf16* __restrict__ Qp, bf16* __restrict__ Kp, bf16* __restrict__ Vp,
    const int* __restrict__ mask, uint* __restrict__ M2) {
  __shared__ __align__(16) unsigned char smem[18432];
  const int tid = threadIdx.x;

  if (blockIdx.x < 1024) {
    // ---- pack_mask: 32 q x 1024 k tile; 16 int4 loads in flight per batch ----
    uint* trans = (uint*)smem;                    // [32 kdw][36 pitch] dwords
    const int pid = blockIdx.x;
    const int bb = pid >> 9;
    const int qt = (pid >> 2) & 127;
    const int kc = pid & 3;
    const int q0 = qt * 32;
    const int w = tid >> 6, l = tid & 63;
    const int d2 = l & 7;
    const int sh = 8 * d2;
    for (int batch = 0; batch < 2; ++batch) {
      int4v m[16];
#pragma unroll
      for (int u = 0; u < 16; ++u) {
        const int q_l = w * 8 + batch * 4 + (u >> 2);
        const int c = u & 3;
        m[u] = *(const int4v*)(mask + ((size_t)(bb * 4096 + q0 + q_l)) * 4096 +
                               kc * 1024 + c * 256 + 4 * l);
      }
#pragma unroll
      for (int u = 0; u < 16; ++u) {
        const int q_l = w * 8 + batch * 4 + (u >> 2);
        const int c = u & 3;
        uint out = 0;
#pragma unroll
        for (int i = 0; i < 4; ++i) {
          ull b = __ballot(m[u][i] != 0);
          out |= ((uint)(b >> sh) & 0xFFu) << (8 * i);
        }
        if (l < 8) trans[(c * 8 + d2) * 36 + q_l] = out;
      }
    }
    __syncthreads();
    {
      const int r = tid >> 3, c4 = (tid & 7) * 4;
      int4v a = *(const int4v*)(trans + r * 36 + c4);
      *(int4v*)(M2 + ((size_t)(bb * 128 + kc * 32 + r)) * 4096 + q0 + c4) = a;
    }
    return;
  }

  // ---- proj: 64 pos x 128 cols tile, epilogue through LDS for coalesced stores ----
  const int pb = blockIdx.x - 1024;
  const int z = pb >> 8;
  const int r8 = pb & 255;
  const int m0 = (r8 >> 1) * 64, n0 = (r8 & 1) * 128;
  const float* X = z == 0 ? xq : (z == 1 ? xk : xv);
  const bf16* wt = WT + (size_t)z * 65536;
  const int wave = tid >> 6, lane = tid & 63;
  const int nl = lane & 15, quad = lane >> 4;
  const int arow = m0 + wave * 16 + nl;
  const float* xrow = X + (size_t)arow * 256;

  f32x4 zero4 = {0.f, 0.f, 0.f, 0.f};
  f32x4 acc[8];
#pragma unroll
  for (int i = 0; i < 8; ++i) acc[i] = zero4;

  for (int ks = 0; ks < 8; ++ks) {
    float4v a0 = *(const float4v*)(xrow + ks * 32 + quad * 8);
    float4v a1 = *(const float4v*)(xrow + ks * 32 + quad * 8 + 4);
    bf16x8 af;
#pragma unroll
    for (int i = 0; i < 4; ++i) { af[i] = (bf16)a0[i]; af[4 + i] = (bf16)a1[i]; }
#pragma unroll
    for (int nf = 0; nf < 8; ++nf) {
      bf16x8 bfr = *(const bf16x8*)(wt + (size_t)(n0 + nf * 16 + nl) * 256 + ks * 32 + quad * 8);
      acc[nf] = __builtin_amdgcn_mfma_f32_16x16x32_bf16(af, bfr, acc[nf], 0, 0, 0);
    }
  }

  const int bq = m0 >> 12;
  const int s0 = m0 & 4095;
  const int posl = wave * 16 + quad * 4;

  if (z == 2) {
    bf16* tv = (bf16*)smem;                       // [col(128)][key(64)+8] pitch 72
#pragma unroll
    for (int nf = 0; nf < 8; ++nf) {
      const int col = nf * 16 + nl;
      bf16x4 o;
#pragma unroll
      for (int rr = 0; rr < 4; ++rr) o[rr] = (bf16)acc[nf][rr];
      *(bf16x4*)(tv + (size_t)col * 72 + posl) = o;
    }
    __syncthreads();
    const int h2 = tid >> 6, ln = tid & 63;
    const int d = ln & 31, shalf = ln >> 5;
    const int h = (n0 >> 5) + h2;
    bf16* vb = Vp + (size_t)(bq * 8 + h) * 131072 + (size_t)(s0 >> 5) * 1024 + d * 8;
#pragma unroll
    for (int it = 0; it < 4; ++it) {
      const int blk = it >> 1, sub = (it & 1) * 2 + shalf;
      const int K0 = (sub >> 1) * 16 + (sub & 1) * 4;
      const bf16* src = tv + (size_t)(h2 * 32 + d) * 72 + blk * 32 + K0;
      bf16x4 g0 = *(const bf16x4*)(src);
      bf16x4 g1 = *(const bf16x4*)(src + 8);
      bf16x8 o;
#pragma unroll
      for (int j = 0; j < 4; ++j) { o[j] = g0[j]; o[4 + j] = g1[j]; }
      *(bf16x8*)(vb + (size_t)blk * 1024 + sub * 256) = o;
    }
  } else {
    bf16* tq = (bf16*)smem;                       // [pos(64)][col(128)+8] pitch 136
    const float scale = (z == 0) ? QSCALE : 1.0f;
#pragma unroll
    for (int nf = 0; nf < 8; ++nf) {
      const int col = nf * 16 + nl;
#pragma unroll
      for (int rr = 0; rr < 4; ++rr)
        tq[(size_t)(posl + rr) * 136 + col] = (bf16)(acc[nf][rr] * scale);
    }
    __syncthreads();
    bf16* Out = z == 0 ? Qp : Kp;
    const int h2 = tid >> 6, ln = tid & 63;
    const int h = (n0 >> 5) + h2;
    const int s = s0 + ln;
    bf16* ob = Out + (size_t)(bq * 8 + h) * 131072 + (size_t)(s >> 5) * 1024 + (s & 31) * 8;
#pragma unroll
    for (int sub = 0; sub < 4; ++sub) {
      bf16x8 o = *(const bf16x8*)(tq + (size_t)ln * 136 + h2 * 32 + sub * 8);
      *(bf16x8*)(ob + sub * 256) = o;
    }
  }
}

// ---------------- K3: attention — 4-wave blocks, 32 q per block, 4-way key
// split (wave w: kdw in [32w,32w+32)); R8's verified STEP algebra; LDS
// cross-wave combine epilogue. High occupancy for latency hiding.
__global__ __launch_bounds__(256, 5) void attn_kernel(
    const bf16* __restrict__ Qp, const bf16* __restrict__ Kp,
    const bf16* __restrict__ Vp, const uint* __restrict__ M2,
    bf16* __restrict__ Og) {
  const int id = blockIdx.x;
  const int xcd = id & 7, slot = id >> 3;    // slot in [0,256)
  const int bh = xcd * 2 + (slot >> 7);      // 2 bh per XCD -> L2-resident K/V/mask
  const int qt = slot & 127;                 // 32-q tile
  const int b = bh >> 3, h = bh & 7;
  const int tid = threadIdx.x, w = tid >> 6, lane = tid & 63;
  const int nl = lane & 31, half = lane >> 5;

  __shared__ __align__(16) float Ored[4][32][36];  // 18.4 KB
  __shared__ float Lsum[4][32];

  const size_t bhbase = (size_t)bh * 131072;
  const int so0 = half * 256 + nl * 8;
  const int so1 = 512 + half * 256 + nl * 8;
  const int qg = qt * 32;

  const bf16* qb = Qp + bhbase + (size_t)qt * 1024;
  const bf16x8 qf0 = *(const bf16x8*)(qb + so0);
  const bf16x8 qf1 = *(const bf16x8*)(qb + so1);

  const bf16* Kb = Kp + bhbase;
  const bf16* Vb = Vp + bhbase;
  const uint* Mb = M2 + (size_t)b * 524288 + qg + nl;

  f32x16 z16;
#pragma unroll
  for (int i = 0; i < 16; ++i) z16[i] = 0.f;
  f32x16 acc = z16, lacc = z16;
  bf16x8 ones;
#pragma unroll
  for (int i = 0; i < 8; ++i) ones[i] = (bf16)1.0f;

  struct Frag { bf16x8 ka0, ka1, va0, va1; uint m; };
  auto LOADF = [&](int kdw) -> Frag {
    Frag f;
    const bf16* kc = Kb + (size_t)kdw * 1024;
    const bf16* vc = Vb + (size_t)kdw * 1024;
    f.ka0 = *(const bf16x8*)(kc + so0);
    f.ka1 = *(const bf16x8*)(kc + so1);
    f.va0 = *(const bf16x8*)(vc + so0);
    f.va1 = *(const bf16x8*)(vc + so1);
    f.m = Mb[(size_t)kdw * 4096];
    return f;
  };

  auto STEP = [&](const Frag& f) {
    const int minv = (int)((~f.m) >> half);
    f32x16 st = __builtin_amdgcn_mfma_f32_32x32x16_bf16(f.ka0, qf0, z16, 0, 0, 0);
    st = __builtin_amdgcn_mfma_f32_32x32x16_bf16(f.ka1, qf1, st, 0, 0, 0);

    uint pk[8];
#pragma unroll
    for (int g = 0; g < 4; ++g)
#pragma unroll
      for (int rp = 0; rp < 2; ++rp) {
        const int i = g * 4 + rp * 2;
        float e0 = __builtin_amdgcn_exp2f(st[i]);
        float e1 = __builtin_amdgcn_exp2f(st[i + 1]);
        const uint k0m = (uint)__builtin_amdgcn_sbfe(minv, 8 * (2 * rp) + 2 * g, 1);
        const uint k1m = (uint)__builtin_amdgcn_sbfe(minv, 8 * (2 * rp + 1) + 2 * g, 1);
        const uint u0 = __float_as_uint(e0) & k0m;
        const uint u1 = __float_as_uint(e1) & k1m;
        pk[g * 2 + rp] = __builtin_amdgcn_perm(u1, u0, 0x07060302u);  // {hi16(u1),hi16(u0)}
      }
    uint4v a0 = {pk[0], pk[1], pk[2], pk[3]};
    uint4v a1 = {pk[4], pk[5], pk[6], pk[7]};
    const bf16x8 pb0 = __builtin_bit_cast(bf16x8, a0);
    const bf16x8 pb1 = __builtin_bit_cast(bf16x8, a1);

    acc  = __builtin_amdgcn_mfma_f32_32x32x16_bf16(f.va0, pb0, acc, 0, 0, 0);
    lacc = __builtin_amdgcn_mfma_f32_32x32x16_bf16(ones,  pb0, lacc, 0, 0, 0);
    acc  = __builtin_amdgcn_mfma_f32_32x32x16_bf16(f.va1, pb1, acc, 0, 0, 0);
    lacc = __builtin_amdgcn_mfma_f32_32x32x16_bf16(ones,  pb1, lacc, 0, 0, 0);
  };

  const int kbase = w * 32;
  Frag fa = LOADF(kbase), fb;
  for (int i = 0; i < 32; i += 2) {
    fb = LOADF(kbase + i + 1);
    STEP(fa);
    if (i + 2 < 32) fa = LOADF(kbase + i + 2);
    STEP(fb);
  }

  // ---- epilogue: cross-wave combine (one-time LDS) ----
#pragma unroll
  for (int g = 0; g < 4; ++g) {
    f32x4 v = {acc[g * 4], acc[g * 4 + 1], acc[g * 4 + 2], acc[g * 4 + 3]};
    *(f32x4*)(&Ored[w][nl][8 * g + 4 * half]) = v;   // d = r + 8g + 4half
  }
  if (half == 0) Lsum[w][nl] = lacc[0];              // all rows of lacc = partial lsum(q)
  __syncthreads();
  {
    const int q = tid >> 3, dc = (tid & 7) * 4;
    f32x4 s = *(const f32x4*)(&Ored[0][q][dc]);
    f32x4 s1 = *(const f32x4*)(&Ored[1][q][dc]);
    f32x4 s2 = *(const f32x4*)(&Ored[2][q][dc]);
    f32x4 s3 = *(const f32x4*)(&Ored[3][q][dc]);
    s += s1; s2 += s3; s += s2;
    const float rl = 1.0f / (Lsum[0][q] + Lsum[1][q] + Lsum[2][q] + Lsum[3][q]);
    bf16x4 o;
#pragma unroll
    for (int r = 0; r < 4; ++r) o[r] = (bf16)(s[r] * rl);
    *(bf16x4*)(Og + ((size_t)(b * 4096 + qg + q)) * 256 + h * 32 + dc) = o;
  }
}

// ---------------- K4: out = attn(bf16) @ w_out -> fp32, 64x64 tiles ----------------
__global__ __launch_bounds__(256) void gemm_out(
    const bf16* __restrict__ A, const bf16* __restrict__ WTo, float* __restrict__ C) {
  const int m0 = blockIdx.x * 64, n0 = blockIdx.y * 64;
  const int tid = threadIdx.x, wave = tid >> 6, lane = tid & 63;
  const int nl = lane & 15, quad = lane >> 4;
  const int arow = m0 + wave * 16 + nl;

  f32x4 zero4 = {0.f, 0.f, 0.f, 0.f};
  f32x4 acc[4];
#pragma unroll
  for (int i = 0; i < 4; ++i) acc[i] = zero4;

  for (int ks = 0; ks < 8; ++ks) {
    bf16x8 af = *(const bf16x8*)(A + (size_t)arow * 256 + ks * 32 + quad * 8);
#pragma unroll
    for (int nf = 0; nf < 4; ++nf) {
      bf16x8 bfr = *(const bf16x8*)(WTo + (size_t)(n0 + nf * 16 + nl) * 256 + ks * 32 + quad * 8);
      acc[nf] = __builtin_amdgcn_mfma_f32_16x16x32_bf16(af, bfr, acc[nf], 0, 0, 0);
    }
  }
  const int Rbase = m0 + wave * 16 + quad * 4;
#pragma unroll
  for (int nf = 0; nf < 4; ++nf)
#pragma unroll
    for (int r = 0; r < 4; ++r)
      C[(size_t)(Rbase + r) * 256 + n0 + nf * 16 + nl] = acc[nf][r];
}

extern "C" void kernel_launch(void* const* d_in, const int* in_sizes, int n_in,
                              void* d_out, int out_size, void* d_ws, size_t ws_size,
                              hipStream_t stream) {
  const float* q  = (const float*)d_in[0];
  const float* k  = (const float*)d_in[1];
  const float* v  = (const float*)d_in[2];
  const int*  mask = (const int*)d_in[3];
  const float* wq = (const float*)d_in[4];
  const float* wk = (const float*)d_in[5];
  const float* wv = (const float*)d_in[6];
  const float* wo = (const float*)d_in[7];
  float* out = (float*)d_out;

  uint8_t* ws = (uint8_t*)d_ws;
  bf16* WT = (bf16*)ws;                               // 512 KB
  bf16* Qp = (bf16*)(ws + (512u << 10));              // frag-native 4 MB
  bf16* Kp = Qp + 2097152;                            // 4 MB
  bf16* Vp = Kp + 2097152;                            // 4 MB
  uint* Mb = (uint*)((uint8_t*)(Vp + 2097152));       // packed mask (permuted bits) 4 MB
  bf16* Ao = (bf16*)((uint8_t*)Mb + (4u << 20));      // attn bf16 [B,S,256] 4 MB

  transpose_w<<<dim3(4, 4, 4), 256, 0, stream>>>(wq, wk, wv, wo, WT);
  proj_pack<<<dim3(1024 + 768), 256, 0, stream>>>(q, k, v, WT, Qp, Kp, Vp, mask, Mb);
  attn_kernel<<<dim3(2048), 256, 0, stream>>>(Qp, Kp, Vp, Mb, Ao);
  gemm_out<<<dim3(128, 4), 256, 0, stream>>>(Ao, WT + 3 * 65536, out);
}